// Round 16
// baseline (74.026 us; speedup 1.0000x reference)
//
#include <hip/hip_runtime.h>

// StyleGAN3 filtered_lrelu, fused. R16 = R11 staged structure with a
// vectorized, mask-free halo stage:
//   halo: 12 image-aligned quads x 42 rows; 1 aligned global float4 +
//         1 ds_write_b128 per task; NO masks (A folds row mask into taps,
//         col-quad mask qf into taps -- both validated in R15).
//   A: reads XS aligned b128 (stride 52 = 13 quads, 5 mod 8 -> spread),
//      writes VS2 shifted (phys dword = halo_col + 3), stride 52.
//   B: R15's validated 4x aligned b128 window read (dwords 8q..8q+15,
//      consumes 3..15).
//   C/D: identical to verified R11.
//
// Math (identical to verified R1..R11):
//   fk[t] = f[11-t];  fkU[t] = 2*fk[t]
//   up (per axis): v[i] = sum_{s<6} fkU[2s + (1-(i&1))] * src[(i>>1)+s]
//   leaky relu slope 0.01 between up and down
//   down (per axis): out[o] = sum_{t<12} fk[t] * z[2o+t]
//
// LDS (dwords): VS2@0 [37][52] f16x2 row-parity (dead after B);
// ZS@1924 [74][40] f16x2 col-parity (dwords>=37 garbage-ok, D reads <=36);
// XS@1924 f32 [42][52] image-aligned quads (halo; inside ZS region, dead
// after A, before B writes ZS); WS@0 [32][44] f16x2 (VS2 dead by C).
// total 4884 dw = 19536 B <= 19968 -> 8 blocks/CU.

#define TAPS 12
#define VS2 0
#define VSS2 52
#define ZS 1924
#define ZSS 40
#define XS 1924
#define XSS 52
#define WS 0
#define WSS 44
#define LDS_DW 4884

typedef _Float16 half_t;
typedef half_t h2 __attribute__((ext_vector_type(2)));
typedef __fp16 g2 __attribute__((ext_vector_type(2)));
typedef float f2 __attribute__((ext_vector_type(2)));

__device__ __forceinline__ h2 u2h(unsigned u){ h2 r; __builtin_memcpy(&r, &u, 4); return r; }
__device__ __forceinline__ g2 u2g(unsigned u){ g2 r; __builtin_memcpy(&r, &u, 4); return r; }
__device__ __forceinline__ unsigned h2du(h2 h){ unsigned u; __builtin_memcpy(&u, &h, 4); return u; }
__device__ __forceinline__ unsigned pkrtz_u(float lo, float hi){
    g2 p = __builtin_amdgcn_cvt_pkrtz(lo, hi);
    unsigned u; __builtin_memcpy(&u, &p, 4); return u;
}
__device__ __forceinline__ h2 h2s(float v){ h2 r; r.x = (half_t)v; r.y = r.x; return r; }
__device__ __forceinline__ unsigned pack2(half_t a, half_t b){ h2 t; t.x=a; t.y=b; return h2du(t); }

__global__ __launch_bounds__(256) void flrelu_fused(
    const float* __restrict__ x, const float* __restrict__ f, float* __restrict__ out)
{
    __shared__ float smem[LDS_DW];
    unsigned* smemu = reinterpret_cast<unsigned*>(smem);

    const int tid = threadIdx.x;
    const int nc  = blockIdx.y;
    const int ho0 = (blockIdx.x >> 2) * 32;
    const int wo0 = (blockIdx.x & 3) * 32;

    float fkU[TAPS];
#pragma unroll
    for (int t = 0; t < TAPS; ++t) fkU[t] = 2.0f * f[TAPS - 1 - t];

    const float* xin = x + (size_t)nc * (128 * 128);

    // ---- halo: 12 aligned quads x 42 rows -> XS, mask-free ----
    // XS phys dword 4q+e = image col (wo0-8+4q+e) = halo col 4q+e-3.
    // Row/col OOB data stored clamped (garbage) -- neutralized in A.
#pragma unroll
    for (int it = 0; it < 2; ++it) {
        int task = tid + 256 * it;
        if (task < 504) {
            int q = task % 12, r = task / 12;
            int gA = wo0 - 8 + 4 * q;
            int gcc = gA < 0 ? 0 : (gA > 124 ? 124 : gA);
            int gr = ho0 - 5 + r;
            int grc = gr < 0 ? 0 : (gr > 127 ? 127 : gr);
            float4 v = *(const float4*)(xin + grc * 128 + gcc);
            *(float4*)(smem + XS + r * XSS + 4 * q) = v;
        }
    }
    __syncthreads();

    // ---- A: vertical up (XS f32 -> VS2 f16 row-parity pairs) ----
    // task=(cq<12, mc<19): v row-pair m=2mc, 2mc+1 at phys dwords 4cq..4cq+3.
    // qf (col-quad OOB) folded into taps; rowf folded per-row.
    if (tid < 228) {
        int cq = tid % 12, mc = tid / 12;
        int gA = wo0 - 8 + 4 * cq;
        float qf = ((unsigned)gA <= 124u) ? 1.f : 0.f;
        f2 tap2[6];
#pragma unroll
        for (int s = 0; s < 6; ++s) { tap2[s].x = fkU[2*s+1] * qf; tap2[s].y = fkU[2*s] * qf; }
        f2 acc0[4], acc1[4];
#pragma unroll
        for (int c = 0; c < 4; ++c) { acc0[c].x=0.f; acc0[c].y=0.f; acc1[c].x=0.f; acc1[c].y=0.f; }
#pragma unroll
        for (int s = 0; s < 7; ++s) {
            int r = 2 * mc + s; r = r < 42 ? r : 41;   // clamped row feeds only skipped m
            int gr = ho0 - 5 + 2 * mc + s;
            float rowf = ((unsigned)gr < 128u) ? 1.f : 0.f;
            float4 xr = *(const float4*)(smem + XS + r * XSS + 4 * cq);
            if (s < 6) {
                f2 t = tap2[s] * rowf;
                acc0[0] += t * xr.x; acc0[1] += t * xr.y;
                acc0[2] += t * xr.z; acc0[3] += t * xr.w;
            }
            if (s >= 1) {
                f2 t = tap2[s - 1] * rowf;
                acc1[0] += t * xr.x; acc1[1] += t * xr.y;
                acc1[2] += t * xr.z; acc1[3] += t * xr.w;
            }
        }
        int m0 = 2 * mc;
        unsigned* vp0 = smemu + VS2 + m0 * VSS2 + 4 * cq;
        *(uint4*)vp0 = make_uint4(pkrtz_u(acc0[0].x, acc0[0].y),
                                  pkrtz_u(acc0[1].x, acc0[1].y),
                                  pkrtz_u(acc0[2].x, acc0[2].y),
                                  pkrtz_u(acc0[3].x, acc0[3].y));
        if (m0 + 1 < 37) {
            unsigned* vp1 = vp0 + VSS2;
            *(uint4*)vp1 = make_uint4(pkrtz_u(acc1[0].x, acc1[0].y),
                                      pkrtz_u(acc1[1].x, acc1[1].y),
                                      pkrtz_u(acc1[2].x, acc1[2].y),
                                      pkrtz_u(acc1[3].x, acc1[3].y));
        }
    }
    __syncthreads();

    // ---- B: horizontal up + lrelu (VS2 f16 -> ZS f16), packed f16 FMA ----
    // task=(m<37, chunk q<5): z rows 2m,2m+1, cols 16q..16q+15.
    // vc[k] = halo col 8q+k = VS2 phys dword 8q+3+k (k=0..12).
    if (tid < 185) {
        int q = tid % 5, m = tid / 5;
        const unsigned* vb = smemu + VS2 + m * VSS2 + 8 * q;
        uint4 rr0 = *(const uint4*)(vb);
        uint4 rr1 = *(const uint4*)(vb + 4);
        uint4 rr2 = *(const uint4*)(vb + 8);
        uint4 rr3 = *(const uint4*)(vb + 12);
        h2 vc[13] = { u2h(rr0.w),
                      u2h(rr1.x), u2h(rr1.y), u2h(rr1.z), u2h(rr1.w),
                      u2h(rr2.x), u2h(rr2.y), u2h(rr2.z), u2h(rr2.w),
                      u2h(rr3.x), u2h(rr3.y), u2h(rr3.z), u2h(rr3.w) };
        h2 fo[6], fe[6];
#pragma unroll
        for (int s = 0; s < 6; ++s) { fo[s] = h2s(fkU[2*s+1]); fe[s] = h2s(fkU[2*s]); }
        h2 sl = h2s(0.01f);
        unsigned pk0[8], pk1[8];
#pragma unroll
        for (int h = 0; h < 8; ++h) {        // z cols 16q+2h (even), +1 (odd)
            h2 ae = h2s(0.f), ao = h2s(0.f); // lanes: .x=row 2m, .y=row 2m+1
#pragma unroll
            for (int s = 0; s < 6; ++s) {
                ae += vc[h + s] * fo[s];
                ao += vc[h + s] * fe[s];
            }
            ae = __builtin_elementwise_max(ae, ae * sl);
            ao = __builtin_elementwise_max(ao, ao * sl);
            pk0[h] = pack2(ae.x, ao.x);      // row 2m:   (z_even, z_odd)
            pk1[h] = pack2(ae.y, ao.y);      // row 2m+1: (z_even, z_odd)
        }
        unsigned* z0 = smemu + ZS + (2 * m) * ZSS + 8 * q;
        unsigned* z1 = z0 + ZSS;
        *(uint4*)(z0)     = make_uint4(pk0[0], pk0[1], pk0[2], pk0[3]);
        *(uint4*)(z0 + 4) = make_uint4(pk0[4], pk0[5], pk0[6], pk0[7]);
        *(uint4*)(z1)     = make_uint4(pk1[0], pk1[1], pk1[2], pk1[3]);
        *(uint4*)(z1 + 4) = make_uint4(pk1[4], pk1[5], pk1[6], pk1[7]);
    }
    __syncthreads();

    // ---- C: vertical down (ZS f16 -> WS f16), 4 out rows/task ----
    // task=(col-oct p8<10, row-quad hq<8); reads z rows 8hq..8hq+17.
    if (tid < 80) {
        int p8 = tid % 10, hq = tid / 10;
        h2 fkh[TAPS];
#pragma unroll
        for (int t = 0; t < TAPS; ++t) fkh[t] = h2s(0.5f * fkU[t]);
        h2 acc[4][4];
#pragma unroll
        for (int j = 0; j < 4; ++j)
#pragma unroll
            for (int d = 0; d < 4; ++d) acc[j][d] = h2s(0.f);
        const unsigned* zbase = smemu + ZS + (8 * hq) * ZSS + 4 * p8;
#pragma unroll
        for (int u = 0; u < 18; ++u) {
            uint4 zr = *(const uint4*)(zbase + u * ZSS);
            h2 z0 = u2h(zr.x), z1 = u2h(zr.y), z2 = u2h(zr.z), z3 = u2h(zr.w);
#pragma unroll
            for (int j = 0; j < 4; ++j) {
                int t = u - 2 * j;
                if (t >= 0 && t < TAPS) {
                    h2 tt = fkh[t];
                    acc[j][0] += tt * z0; acc[j][1] += tt * z1;
                    acc[j][2] += tt * z2; acc[j][3] += tt * z3;
                }
            }
        }
        unsigned* wp = smemu + WS + (4 * hq) * WSS + 4 * p8;
#pragma unroll
        for (int j = 0; j < 4; ++j)
            *(uint4*)(wp + j * WSS) = make_uint4(h2du(acc[j][0]), h2du(acc[j][1]),
                                                 h2du(acc[j][2]), h2du(acc[j][3]));
    }
    __syncthreads();

    // ---- D: horizontal down (WS f16 -> global f32) via v_dot2_f32_f16 ----
    {
        int ho = tid >> 3, w4 = tid & 7;
        const unsigned* wp = smemu + WS + ho * WSS + 4 * w4;
        uint4 q0 = *(const uint4*)(wp);
        uint4 q1 = *(const uint4*)(wp + 4);
        unsigned q2 = wp[8];
        unsigned dws[9] = { q0.x, q0.y, q0.z, q0.w, q1.x, q1.y, q1.z, q1.w, q2 };
        unsigned fp[6];
#pragma unroll
        for (int d = 0; d < 6; ++d) fp[d] = pkrtz_u(0.5f * fkU[2*d], 0.5f * fkU[2*d+1]);
        float o[4];
#pragma unroll
        for (int v = 0; v < 4; ++v) {
            float acc = 0.f;
#pragma unroll
            for (int d = 0; d < 6; ++d)
                acc = __builtin_amdgcn_fdot2(u2g(dws[v + d]), u2g(fp[d]), acc, false);
            o[v] = acc;
        }
        *(float4*)(out + ((size_t)nc * 128 + (ho0 + ho)) * 128 + wo0 + 4 * w4)
            = make_float4(o[0], o[1], o[2], o[3]);
    }
}

extern "C" void kernel_launch(void* const* d_in, const int* in_sizes, int n_in,
                              void* d_out, int out_size, void* d_ws, size_t ws_size,
                              hipStream_t stream) {
    const float* x = (const float*)d_in[0];
    const float* f = (const float*)d_in[1];
    float* out = (float*)d_out;
    dim3 grid(16, 1024);
    flrelu_fused<<<grid, 256, 0, stream>>>(x, f, out);
}

// Round 17
// 62.281 us; speedup vs baseline: 1.1886x; 1.1886x over previous
//
#include <hip/hip_runtime.h>

// StyleGAN3 filtered_lrelu, fused. R17 = R11 skeleton with f16 halo:
//   halo: image-aligned float2 -> cvt_pkrtz -> 1 masked ds_write_b32 per
//         pair (16 wave-DS vs 28; zero-padding stays here, A mask-free).
//   A: 7x ds_read_b64 (f16 pairs), packed v_pk_fma_f16, (e,o) v_pack;
//      VS2 phys dword = halo_col + 1 (all accesses aligned).
//   B: R11's reads with components shifted by one dword (vc[k] = phys
//      8q+1+k); over-reads touch only z cols >= 74 (unconsumed).
//   C/D: verbatim R11.
//
// Math (identical to verified R1..R11):
//   fk[t] = f[11-t];  fkU[t] = 2*fk[t]
//   up (per axis): v[i] = sum_{s<6} fkU[2s + (1-(i&1))] * src[(i>>1)+s]
//   leaky relu slope 0.01 between up and down
//   down (per axis): out[o] = sum_{t<12} fk[t] * z[2o+t]
//
// LDS (dwords): VS2@0 [37][44] f16x2 row-parity, phys d = halo col d-1
// (dead after B); ZS@1628 [74][44] f16x2 col-parity (cols>=74 garbage-ok);
// XS2@1628 [42][24] f16 col-pairs, dword p = halo cols {2p-1,2p} (halo,
// dead before B writes ZS); WS@0 [32][44] f16x2 (VS2 dead by C).
// total 4884 dw = 19536 B -> 8 blocks/CU.

#define TAPS 12
#define VS2 0
#define VSS2 44
#define ZS 1628
#define ZSS 44
#define XS2 1628
#define XSS2 24
#define WS 0
#define WSS 44
#define LDS_DW 4884

typedef _Float16 half_t;
typedef half_t h2 __attribute__((ext_vector_type(2)));
typedef __fp16 g2 __attribute__((ext_vector_type(2)));

__device__ __forceinline__ h2 u2h(unsigned u){ h2 r; __builtin_memcpy(&r, &u, 4); return r; }
__device__ __forceinline__ g2 u2g(unsigned u){ g2 r; __builtin_memcpy(&r, &u, 4); return r; }
__device__ __forceinline__ unsigned h2du(h2 h){ unsigned u; __builtin_memcpy(&u, &h, 4); return u; }
__device__ __forceinline__ unsigned pkrtz_u(float lo, float hi){
    g2 p = __builtin_amdgcn_cvt_pkrtz(lo, hi);
    unsigned u; __builtin_memcpy(&u, &p, 4); return u;
}
__device__ __forceinline__ h2 h2s(float v){ h2 r; r.x = (half_t)v; r.y = r.x; return r; }
__device__ __forceinline__ unsigned pack2(half_t a, half_t b){ h2 t; t.x=a; t.y=b; return h2du(t); }

__global__ __launch_bounds__(256) void flrelu_fused(
    const float* __restrict__ x, const float* __restrict__ f, float* __restrict__ out)
{
    __shared__ float smem[LDS_DW];
    unsigned* smemu = reinterpret_cast<unsigned*>(smem);

    const int tid = threadIdx.x;
    const int nc  = blockIdx.y;
    const int ho0 = (blockIdx.x >> 2) * 32;
    const int wo0 = (blockIdx.x & 3) * 32;

    float fkU[TAPS];
#pragma unroll
    for (int t = 0; t < TAPS; ++t) fkU[t] = 2.0f * f[TAPS - 1 - t];

    const float* xin = x + (size_t)nc * (128 * 128);

    // ---- halo: f16 col-pairs -> XS2. task (p<22, r0<11), rows r0+11k ----
    // dword p = image cols (wo0-6+2p, +1) = halo cols (2p-1, 2p); even image
    // col -> aligned float2; pair fully in- or out-of-bounds; masked store.
    if (tid < 242) {
        int p = tid % 22, r0 = tid / 22;
        int ic = wo0 - 6 + 2 * p;
        bool colok = (unsigned)ic < 128u;
        int icc = ic < 0 ? 0 : (ic > 126 ? 126 : ic);
#pragma unroll
        for (int k = 0; k < 4; ++k) {
            int r = r0 + 11 * k;
            if (r < 42) {
                int gr = ho0 - 5 + r;
                int grc = gr < 0 ? 0 : (gr > 127 ? 127 : gr);
                float2 v = *(const float2*)(xin + grc * 128 + icc);
                unsigned pk = pkrtz_u(v.x, v.y);
                bool ok = colok && ((unsigned)gr < 128u);
                smemu[XS2 + r * XSS2 + p] = ok ? pk : 0u;
            }
        }
    }
    __syncthreads();

    // ---- A: vertical up (XS2 f16 -> VS2 f16 row-parity), pk_fma_f16 ----
    // task=(g<11, mc<19): v rows 2mc,2mc+1 at halo cols 4g-1..4g+2
    // (VS2 phys dwords 4g..4g+3). Reads XS2 dwords 2g,2g+1 per row (b64).
    if (tid < 209) {
        int g = tid % 11, mc = tid / 11;
        h2 xa[7], xb[7];
#pragma unroll
        for (int s = 0; s < 7; ++s) {
            int r = 2 * mc + s; r = r < 42 ? r : 41;   // clamped row feeds only skipped m
            uint2 u = *(const uint2*)(smemu + XS2 + r * XSS2 + 2 * g);
            xa[s] = u2h(u.x); xb[s] = u2h(u.y);
        }
        h2 fo[6], fe[6];
#pragma unroll
        for (int s = 0; s < 6; ++s) { fo[s] = h2s(fkU[2*s+1]); fe[s] = h2s(fkU[2*s]); }
#pragma unroll
        for (int k2 = 0; k2 < 2; ++k2) {
            int m = 2 * mc + k2;
            if (m < 37) {
                h2 ea = h2s(0.f), eb = h2s(0.f), oa = h2s(0.f), ob = h2s(0.f);
#pragma unroll
                for (int s = 0; s < 6; ++s) {
                    ea += fo[s] * xa[k2 + s];  eb += fo[s] * xb[k2 + s];
                    oa += fe[s] * xa[k2 + s];  ob += fe[s] * xb[k2 + s];
                }
                // VS2 dword 4g+j = (v_even, v_odd) at halo col 4g-1+j
                unsigned* vp = smemu + VS2 + m * VSS2 + 4 * g;
                *(uint4*)vp = make_uint4(pack2(ea.x, oa.x), pack2(ea.y, oa.y),
                                         pack2(eb.x, ob.x), pack2(eb.y, ob.y));
            }
        }
    }
    __syncthreads();

    // ---- B: horizontal up + lrelu (VS2 f16 -> ZS f16), packed f16 FMA ----
    // task=(m<37, chunk q<5): z rows 2m,2m+1, cols 16q..16q+15.
    // vc[k] = halo col 8q+k = VS2 phys dword 8q+1+k.
    if (tid < 185) {
        int q = tid % 5, m = tid / 5;
        const unsigned* vb = smemu + VS2 + m * VSS2 + 8 * q;
        uint4 rr0 = *(const uint4*)(vb);
        uint4 rr1 = *(const uint4*)(vb + 4);
        uint4 rr2 = *(const uint4*)(vb + 8);
        uint2 rr3 = *(const uint2*)(vb + 12);
        h2 vc[13] = { u2h(rr0.y), u2h(rr0.z), u2h(rr0.w),
                      u2h(rr1.x), u2h(rr1.y), u2h(rr1.z), u2h(rr1.w),
                      u2h(rr2.x), u2h(rr2.y), u2h(rr2.z), u2h(rr2.w),
                      u2h(rr3.x), u2h(rr3.y) };
        h2 fo[6], fe[6];
#pragma unroll
        for (int s = 0; s < 6; ++s) { fo[s] = h2s(fkU[2*s+1]); fe[s] = h2s(fkU[2*s]); }
        h2 sl = h2s(0.01f);
        unsigned pk0[8], pk1[8];
#pragma unroll
        for (int h = 0; h < 8; ++h) {        // z cols 16q+2h (even), +1 (odd)
            h2 ae = h2s(0.f), ao = h2s(0.f); // lanes: .x=row 2m, .y=row 2m+1
#pragma unroll
            for (int s = 0; s < 6; ++s) {
                ae += vc[h + s] * fo[s];
                ao += vc[h + s] * fe[s];
            }
            ae = __builtin_elementwise_max(ae, ae * sl);
            ao = __builtin_elementwise_max(ao, ao * sl);
            pk0[h] = pack2(ae.x, ao.x);      // row 2m:   (z_even, z_odd)
            pk1[h] = pack2(ae.y, ao.y);      // row 2m+1: (z_even, z_odd)
        }
        unsigned* z0 = smemu + ZS + (2 * m) * ZSS + 8 * q;
        unsigned* z1 = z0 + ZSS;
        *(uint4*)(z0)     = make_uint4(pk0[0], pk0[1], pk0[2], pk0[3]);
        *(uint4*)(z0 + 4) = make_uint4(pk0[4], pk0[5], pk0[6], pk0[7]);
        *(uint4*)(z1)     = make_uint4(pk1[0], pk1[1], pk1[2], pk1[3]);
        *(uint4*)(z1 + 4) = make_uint4(pk1[4], pk1[5], pk1[6], pk1[7]);
    }
    __syncthreads();

    // ---- C: vertical down (ZS f16 -> WS f16), 4 out rows/task ----
    // task=(col-oct p8<10, row-quad hq<8); reads z rows 8hq..8hq+17.
    if (tid < 80) {
        int p8 = tid % 10, hq = tid / 10;
        h2 fkh[TAPS];
#pragma unroll
        for (int t = 0; t < TAPS; ++t) fkh[t] = h2s(0.5f * fkU[t]);
        h2 acc[4][4];
#pragma unroll
        for (int j = 0; j < 4; ++j)
#pragma unroll
            for (int d = 0; d < 4; ++d) acc[j][d] = h2s(0.f);
        const unsigned* zbase = smemu + ZS + (8 * hq) * ZSS + 4 * p8;
#pragma unroll
        for (int u = 0; u < 18; ++u) {
            uint4 zr = *(const uint4*)(zbase + u * ZSS);
            h2 z0 = u2h(zr.x), z1 = u2h(zr.y), z2 = u2h(zr.z), z3 = u2h(zr.w);
#pragma unroll
            for (int j = 0; j < 4; ++j) {
                int t = u - 2 * j;
                if (t >= 0 && t < TAPS) {
                    h2 tt = fkh[t];
                    acc[j][0] += tt * z0; acc[j][1] += tt * z1;
                    acc[j][2] += tt * z2; acc[j][3] += tt * z3;
                }
            }
        }
        unsigned* wp = smemu + WS + (4 * hq) * WSS + 4 * p8;
#pragma unroll
        for (int j = 0; j < 4; ++j)
            *(uint4*)(wp + j * WSS) = make_uint4(h2du(acc[j][0]), h2du(acc[j][1]),
                                                 h2du(acc[j][2]), h2du(acc[j][3]));
    }
    __syncthreads();

    // ---- D: horizontal down (WS f16 -> global f32) via v_dot2_f32_f16 ----
    {
        int ho = tid >> 3, w4 = tid & 7;
        const unsigned* wp = smemu + WS + ho * WSS + 4 * w4;
        uint4 q0 = *(const uint4*)(wp);
        uint4 q1 = *(const uint4*)(wp + 4);
        unsigned q2 = wp[8];
        unsigned dws[9] = { q0.x, q0.y, q0.z, q0.w, q1.x, q1.y, q1.z, q1.w, q2 };
        unsigned fp[6];
#pragma unroll
        for (int d = 0; d < 6; ++d) fp[d] = pkrtz_u(0.5f * fkU[2*d], 0.5f * fkU[2*d+1]);
        float o[4];
#pragma unroll
        for (int v = 0; v < 4; ++v) {
            float acc = 0.f;
#pragma unroll
            for (int d = 0; d < 6; ++d)
                acc = __builtin_amdgcn_fdot2(u2g(dws[v + d]), u2g(fp[d]), acc, false);
            o[v] = acc;
        }
        *(float4*)(out + ((size_t)nc * 128 + (ho0 + ho)) * 128 + wo0 + 4 * w4)
            = make_float4(o[0], o[1], o[2], o[3]);
    }
}

extern "C" void kernel_launch(void* const* d_in, const int* in_sizes, int n_in,
                              void* d_out, int out_size, void* d_ws, size_t ws_size,
                              hipStream_t stream) {
    const float* x = (const float*)d_in[0];
    const float* f = (const float*)d_in[1];
    float* out = (float*)d_out;
    dim3 grid(16, 1024);
    flrelu_fused<<<grid, 256, 0, stream>>>(x, f, out);
}

// Round 18
// 62.214 us; speedup vs baseline: 1.1899x; 1.0011x over previous
//
#include <hip/hip_runtime.h>

// StyleGAN3 filtered_lrelu, fused. R18 = R17 with XS2 stride 24 -> 26.
// R17's A-stage b64 reads had mc-group step 48 dw == 16 mod 32 -> 3-way
// bank aliasing (conflicts rose 1.06e7 -> 1.37e7). Stride 26: pair-step
// 10mc mod 16 = {0,10,4,14,8,2} all distinct -> flat bank spread.
//   halo: image-aligned float2 -> cvt_pkrtz -> 1 masked ds_write_b32/pair.
//   A: 7x ds_read_b64 (f16 pairs), packed v_pk_fma_f16, (e,o) v_pack;
//      VS2 phys dword = halo_col + 1.
//   B: reads shifted by one dword (vc[k] = phys 8q+1+k); over-reads land
//      only in z cols >= 74 (unconsumed).
//   C/D: verbatim R11.
//
// Math (identical to verified R1..R11):
//   fk[t] = f[11-t];  fkU[t] = 2*fk[t]
//   up (per axis): v[i] = sum_{s<6} fkU[2s + (1-(i&1))] * src[(i>>1)+s]
//   leaky relu slope 0.01 between up and down
//   down (per axis): out[o] = sum_{t<12} fk[t] * z[2o+t]
//
// LDS (dwords): VS2@0 [37][44] f16x2 row-parity, phys d = halo col d-1
// (dead after B); ZS@1628 [74][44] f16x2 col-parity (cols>=74 garbage-ok);
// XS2@1628 [42][26] f16 col-pairs, dword p = halo cols {2p-1,2p} (halo,
// 1092 dw inside ZS region, dead before B writes ZS); WS@0 [32][44] f16x2
// (VS2 dead by C). total 4884 dw = 19536 B -> 8 blocks/CU.

#define TAPS 12
#define VS2 0
#define VSS2 44
#define ZS 1628
#define ZSS 44
#define XS2 1628
#define XSS2 26
#define WS 0
#define WSS 44
#define LDS_DW 4884

typedef _Float16 half_t;
typedef half_t h2 __attribute__((ext_vector_type(2)));
typedef __fp16 g2 __attribute__((ext_vector_type(2)));

__device__ __forceinline__ h2 u2h(unsigned u){ h2 r; __builtin_memcpy(&r, &u, 4); return r; }
__device__ __forceinline__ g2 u2g(unsigned u){ g2 r; __builtin_memcpy(&r, &u, 4); return r; }
__device__ __forceinline__ unsigned h2du(h2 h){ unsigned u; __builtin_memcpy(&u, &h, 4); return u; }
__device__ __forceinline__ unsigned pkrtz_u(float lo, float hi){
    g2 p = __builtin_amdgcn_cvt_pkrtz(lo, hi);
    unsigned u; __builtin_memcpy(&u, &p, 4); return u;
}
__device__ __forceinline__ h2 h2s(float v){ h2 r; r.x = (half_t)v; r.y = r.x; return r; }
__device__ __forceinline__ unsigned pack2(half_t a, half_t b){ h2 t; t.x=a; t.y=b; return h2du(t); }

__global__ __launch_bounds__(256) void flrelu_fused(
    const float* __restrict__ x, const float* __restrict__ f, float* __restrict__ out)
{
    __shared__ float smem[LDS_DW];
    unsigned* smemu = reinterpret_cast<unsigned*>(smem);

    const int tid = threadIdx.x;
    const int nc  = blockIdx.y;
    const int ho0 = (blockIdx.x >> 2) * 32;
    const int wo0 = (blockIdx.x & 3) * 32;

    float fkU[TAPS];
#pragma unroll
    for (int t = 0; t < TAPS; ++t) fkU[t] = 2.0f * f[TAPS - 1 - t];

    const float* xin = x + (size_t)nc * (128 * 128);

    // ---- halo: f16 col-pairs -> XS2. task (p<22, r0<11), rows r0+11k ----
    // dword p = image cols (wo0-6+2p, +1) = halo cols (2p-1, 2p); even image
    // col -> aligned float2; pair fully in- or out-of-bounds; masked store.
    if (tid < 242) {
        int p = tid % 22, r0 = tid / 22;
        int ic = wo0 - 6 + 2 * p;
        bool colok = (unsigned)ic < 128u;
        int icc = ic < 0 ? 0 : (ic > 126 ? 126 : ic);
#pragma unroll
        for (int k = 0; k < 4; ++k) {
            int r = r0 + 11 * k;
            if (r < 42) {
                int gr = ho0 - 5 + r;
                int grc = gr < 0 ? 0 : (gr > 127 ? 127 : gr);
                float2 v = *(const float2*)(xin + grc * 128 + icc);
                unsigned pk = pkrtz_u(v.x, v.y);
                bool ok = colok && ((unsigned)gr < 128u);
                smemu[XS2 + r * XSS2 + p] = ok ? pk : 0u;
            }
        }
    }
    __syncthreads();

    // ---- A: vertical up (XS2 f16 -> VS2 f16 row-parity), pk_fma_f16 ----
    // task=(g<11, mc<19): v rows 2mc,2mc+1 at halo cols 4g-1..4g+2
    // (VS2 phys dwords 4g..4g+3). Reads XS2 dwords 2g,2g+1 per row (b64).
    if (tid < 209) {
        int g = tid % 11, mc = tid / 11;
        h2 xa[7], xb[7];
#pragma unroll
        for (int s = 0; s < 7; ++s) {
            int r = 2 * mc + s; r = r < 42 ? r : 41;   // clamped row feeds only skipped m
            uint2 u = *(const uint2*)(smemu + XS2 + r * XSS2 + 2 * g);
            xa[s] = u2h(u.x); xb[s] = u2h(u.y);
        }
        h2 fo[6], fe[6];
#pragma unroll
        for (int s = 0; s < 6; ++s) { fo[s] = h2s(fkU[2*s+1]); fe[s] = h2s(fkU[2*s]); }
#pragma unroll
        for (int k2 = 0; k2 < 2; ++k2) {
            int m = 2 * mc + k2;
            if (m < 37) {
                h2 ea = h2s(0.f), eb = h2s(0.f), oa = h2s(0.f), ob = h2s(0.f);
#pragma unroll
                for (int s = 0; s < 6; ++s) {
                    ea += fo[s] * xa[k2 + s];  eb += fo[s] * xb[k2 + s];
                    oa += fe[s] * xa[k2 + s];  ob += fe[s] * xb[k2 + s];
                }
                // VS2 dword 4g+j = (v_even, v_odd) at halo col 4g-1+j
                unsigned* vp = smemu + VS2 + m * VSS2 + 4 * g;
                *(uint4*)vp = make_uint4(pack2(ea.x, oa.x), pack2(ea.y, oa.y),
                                         pack2(eb.x, ob.x), pack2(eb.y, ob.y));
            }
        }
    }
    __syncthreads();

    // ---- B: horizontal up + lrelu (VS2 f16 -> ZS f16), packed f16 FMA ----
    // task=(m<37, chunk q<5): z rows 2m,2m+1, cols 16q..16q+15.
    // vc[k] = halo col 8q+k = VS2 phys dword 8q+1+k.
    if (tid < 185) {
        int q = tid % 5, m = tid / 5;
        const unsigned* vb = smemu + VS2 + m * VSS2 + 8 * q;
        uint4 rr0 = *(const uint4*)(vb);
        uint4 rr1 = *(const uint4*)(vb + 4);
        uint4 rr2 = *(const uint4*)(vb + 8);
        uint2 rr3 = *(const uint2*)(vb + 12);
        h2 vc[13] = { u2h(rr0.y), u2h(rr0.z), u2h(rr0.w),
                      u2h(rr1.x), u2h(rr1.y), u2h(rr1.z), u2h(rr1.w),
                      u2h(rr2.x), u2h(rr2.y), u2h(rr2.z), u2h(rr2.w),
                      u2h(rr3.x), u2h(rr3.y) };
        h2 fo[6], fe[6];
#pragma unroll
        for (int s = 0; s < 6; ++s) { fo[s] = h2s(fkU[2*s+1]); fe[s] = h2s(fkU[2*s]); }
        h2 sl = h2s(0.01f);
        unsigned pk0[8], pk1[8];
#pragma unroll
        for (int h = 0; h < 8; ++h) {        // z cols 16q+2h (even), +1 (odd)
            h2 ae = h2s(0.f), ao = h2s(0.f); // lanes: .x=row 2m, .y=row 2m+1
#pragma unroll
            for (int s = 0; s < 6; ++s) {
                ae += vc[h + s] * fo[s];
                ao += vc[h + s] * fe[s];
            }
            ae = __builtin_elementwise_max(ae, ae * sl);
            ao = __builtin_elementwise_max(ao, ao * sl);
            pk0[h] = pack2(ae.x, ao.x);      // row 2m:   (z_even, z_odd)
            pk1[h] = pack2(ae.y, ao.y);      // row 2m+1: (z_even, z_odd)
        }
        unsigned* z0 = smemu + ZS + (2 * m) * ZSS + 8 * q;
        unsigned* z1 = z0 + ZSS;
        *(uint4*)(z0)     = make_uint4(pk0[0], pk0[1], pk0[2], pk0[3]);
        *(uint4*)(z0 + 4) = make_uint4(pk0[4], pk0[5], pk0[6], pk0[7]);
        *(uint4*)(z1)     = make_uint4(pk1[0], pk1[1], pk1[2], pk1[3]);
        *(uint4*)(z1 + 4) = make_uint4(pk1[4], pk1[5], pk1[6], pk1[7]);
    }
    __syncthreads();

    // ---- C: vertical down (ZS f16 -> WS f16), 4 out rows/task ----
    // task=(col-oct p8<10, row-quad hq<8); reads z rows 8hq..8hq+17.
    if (tid < 80) {
        int p8 = tid % 10, hq = tid / 10;
        h2 fkh[TAPS];
#pragma unroll
        for (int t = 0; t < TAPS; ++t) fkh[t] = h2s(0.5f * fkU[t]);
        h2 acc[4][4];
#pragma unroll
        for (int j = 0; j < 4; ++j)
#pragma unroll
            for (int d = 0; d < 4; ++d) acc[j][d] = h2s(0.f);
        const unsigned* zbase = smemu + ZS + (8 * hq) * ZSS + 4 * p8;
#pragma unroll
        for (int u = 0; u < 18; ++u) {
            uint4 zr = *(const uint4*)(zbase + u * ZSS);
            h2 z0 = u2h(zr.x), z1 = u2h(zr.y), z2 = u2h(zr.z), z3 = u2h(zr.w);
#pragma unroll
            for (int j = 0; j < 4; ++j) {
                int t = u - 2 * j;
                if (t >= 0 && t < TAPS) {
                    h2 tt = fkh[t];
                    acc[j][0] += tt * z0; acc[j][1] += tt * z1;
                    acc[j][2] += tt * z2; acc[j][3] += tt * z3;
                }
            }
        }
        unsigned* wp = smemu + WS + (4 * hq) * WSS + 4 * p8;
#pragma unroll
        for (int j = 0; j < 4; ++j)
            *(uint4*)(wp + j * WSS) = make_uint4(h2du(acc[j][0]), h2du(acc[j][1]),
                                                 h2du(acc[j][2]), h2du(acc[j][3]));
    }
    __syncthreads();

    // ---- D: horizontal down (WS f16 -> global f32) via v_dot2_f32_f16 ----
    {
        int ho = tid >> 3, w4 = tid & 7;
        const unsigned* wp = smemu + WS + ho * WSS + 4 * w4;
        uint4 q0 = *(const uint4*)(wp);
        uint4 q1 = *(const uint4*)(wp + 4);
        unsigned q2 = wp[8];
        unsigned dws[9] = { q0.x, q0.y, q0.z, q0.w, q1.x, q1.y, q1.z, q1.w, q2 };
        unsigned fp[6];
#pragma unroll
        for (int d = 0; d < 6; ++d) fp[d] = pkrtz_u(0.5f * fkU[2*d], 0.5f * fkU[2*d+1]);
        float o[4];
#pragma unroll
        for (int v = 0; v < 4; ++v) {
            float acc = 0.f;
#pragma unroll
            for (int d = 0; d < 6; ++d)
                acc = __builtin_amdgcn_fdot2(u2g(dws[v + d]), u2g(fp[d]), acc, false);
            o[v] = acc;
        }
        *(float4*)(out + ((size_t)nc * 128 + (ho0 + ho)) * 128 + wo0 + 4 * w4)
            = make_float4(o[0], o[1], o[2], o[3]);
    }
}

extern "C" void kernel_launch(void* const* d_in, const int* in_sizes, int n_in,
                              void* d_out, int out_size, void* d_ws, size_t ws_size,
                              hipStream_t stream) {
    const float* x = (const float*)d_in[0];
    const float* f = (const float*)d_in[1];
    float* out = (float*)d_out;
    dim3 grid(16, 1024);
    flrelu_fused<<<grid, 256, 0, stream>>>(x, f, out);
}

// Round 19
// 62.197 us; speedup vs baseline: 1.1902x; 1.0003x over previous
//
#include <hip/hip_runtime.h>

// StyleGAN3 filtered_lrelu, fused. R19 = R11 with vertically-packed f16 halo:
//   XP[p][c] = f16x2 (x[2p][c], x[2p+1][c])  (21 row-pairs x 42 halo cols)
//   halo: 441 tasks, 4 scalar global loads + 2 cvt_pkrtz + 1 ds_write_b64
//         (masking per-component here; A is mask-free). 7 wave-DS vs 28.
//   A: 4x ds_read_b128 (pairs mc..mc+3, clamp 20) vs 7; vertical 6-tap FIR
//      via v_dot2_f32_f16: k2=0 aligned -> 6 fdot2/col; k2=1 straddle ->
//      edge pair (hi P0, lo P3) + 6 fdot2/col. Taps wave-uniform.
//      VS2 dword (m, col) = (v[2m][col], v[2m+1][col])  == R11 semantic.
//   B/C/D: verbatim R11.
// Wave-DS/block: 144 -> 111.
//
// Math (identical to verified R1..R11):
//   fk[t] = f[11-t];  fkU[t] = 2*fk[t]
//   up (per axis): v[i] = sum_{s<6} fkU[2s + (1-(i&1))] * src[(i>>1)+s]
//   leaky relu slope 0.01 between up and down
//   down (per axis): out[o] = sum_{t<12} fk[t] * z[2o+t]
//
// LDS (dwords): VS2@0 [37][44] (dead after B); ZS@1628 [74][44] f16x2
// col-parity (cols>=74 garbage-ok); XP@1628 [21][44] f16 row-pairs (halo,
// 924 dw inside ZS region, dead before B writes ZS); WS@0 [32][44] f16x2
// (VS2 dead by C). total 4884 dw = 19536 B -> 8 blocks/CU.

#define TAPS 12
#define VS2 0
#define VSS2 44
#define ZS 1628
#define ZSS 44
#define XP 1628
#define XPS 44
#define WS 0
#define WSS 44
#define LDS_DW 4884

typedef _Float16 half_t;
typedef half_t h2 __attribute__((ext_vector_type(2)));
typedef __fp16 g2 __attribute__((ext_vector_type(2)));

__device__ __forceinline__ h2 u2h(unsigned u){ h2 r; __builtin_memcpy(&r, &u, 4); return r; }
__device__ __forceinline__ g2 u2g(unsigned u){ g2 r; __builtin_memcpy(&r, &u, 4); return r; }
__device__ __forceinline__ unsigned h2du(h2 h){ unsigned u; __builtin_memcpy(&u, &h, 4); return u; }
__device__ __forceinline__ unsigned pkrtz_u(float lo, float hi){
    g2 p = __builtin_amdgcn_cvt_pkrtz(lo, hi);
    unsigned u; __builtin_memcpy(&u, &p, 4); return u;
}
__device__ __forceinline__ h2 h2s(float v){ h2 r; r.x = (half_t)v; r.y = r.x; return r; }
__device__ __forceinline__ unsigned pack2(half_t a, half_t b){ h2 t; t.x=a; t.y=b; return h2du(t); }

__global__ __launch_bounds__(256) void flrelu_fused(
    const float* __restrict__ x, const float* __restrict__ f, float* __restrict__ out)
{
    __shared__ float smem[LDS_DW];
    unsigned* smemu = reinterpret_cast<unsigned*>(smem);

    const int tid = threadIdx.x;
    const int nc  = blockIdx.y;
    const int ho0 = (blockIdx.x >> 2) * 32;
    const int wo0 = (blockIdx.x & 3) * 32;

    float fkU[TAPS];
#pragma unroll
    for (int t = 0; t < TAPS; ++t) fkU[t] = 2.0f * f[TAPS - 1 - t];

    const float* xin = x + (size_t)nc * (128 * 128);

    // ---- halo: vertical f16 row-pairs -> XP. task=(c2<21, p<21) ----
    // cols 2c2, 2c2+1; rows 2p, 2p+1 (halo-relative); per-component masks.
#pragma unroll
    for (int it = 0; it < 2; ++it) {
        int task = tid + 256 * it;
        if (task < 441) {
            int c2 = task % 21, p = task / 21;
            int ic0 = wo0 - 5 + 2 * c2, ic1 = ic0 + 1;
            int g0 = ho0 - 5 + 2 * p, g1 = g0 + 1;
            int g0c = g0 < 0 ? 0 : (g0 > 127 ? 127 : g0);
            int g1c = g1 < 0 ? 0 : (g1 > 127 ? 127 : g1);
            int ic0c = ic0 < 0 ? 0 : (ic0 > 127 ? 127 : ic0);
            int ic1c = ic1 < 0 ? 0 : (ic1 > 127 ? 127 : ic1);
            const float* r0p = xin + g0c * 128;
            const float* r1p = xin + g1c * 128;
            float x00 = r0p[ic0c], x01 = r0p[ic1c];
            float x10 = r1p[ic0c], x11 = r1p[ic1c];
            bool r0ok = (unsigned)g0 < 128u, r1ok = (unsigned)g1 < 128u;
            bool c0ok = (unsigned)ic0 < 128u, c1ok = (unsigned)ic1 < 128u;
            x00 = (r0ok && c0ok) ? x00 : 0.f;
            x10 = (r1ok && c0ok) ? x10 : 0.f;
            x01 = (r0ok && c1ok) ? x01 : 0.f;
            x11 = (r1ok && c1ok) ? x11 : 0.f;
            unsigned d0 = pkrtz_u(x00, x10);   // col 2c2:   (row 2p, row 2p+1)
            unsigned d1 = pkrtz_u(x01, x11);   // col 2c2+1
            *(uint2*)(smemu + XP + p * XPS + 2 * c2) = make_uint2(d0, d1);
        }
    }
    __syncthreads();

    // ---- A: vertical up (XP f16 pairs -> VS2), fdot2. task=(cq<11, mc<19) ----
    // reads pairs mc..mc+3 (clamp 20; clamped pair feeds only skipped m) at
    // cols 4cq..4cq+3; computes v rows 2m, 2m+1 for m = 2mc (+1 if < 37).
    if (tid < 209) {
        int cq = tid % 11, mc = tid / 11;
        uint4 P[4];
#pragma unroll
        for (int i = 0; i < 4; ++i) {
            int pp = mc + i; pp = pp < 21 ? pp : 20;
            P[i] = *(const uint4*)(smemu + XP + pp * XPS + 4 * cq);
        }
        unsigned a0[4] = { P[0].x, P[0].y, P[0].z, P[0].w };
        unsigned a1[4] = { P[1].x, P[1].y, P[1].z, P[1].w };
        unsigned a2[4] = { P[2].x, P[2].y, P[2].z, P[2].w };
        unsigned a3[4] = { P[3].x, P[3].y, P[3].z, P[3].w };
        // uniform tap pairs
        unsigned te0 = pkrtz_u(fkU[1], fkU[3]),  te1 = pkrtz_u(fkU[5], fkU[7]),
                 te2 = pkrtz_u(fkU[9], fkU[11]), to0 = pkrtz_u(fkU[0], fkU[2]),
                 to1 = pkrtz_u(fkU[4], fkU[6]),  to2 = pkrtz_u(fkU[8], fkU[10]);
        unsigned se1 = pkrtz_u(fkU[3], fkU[5]),  se2 = pkrtz_u(fkU[7], fkU[9]),
                 so1 = pkrtz_u(fkU[2], fkU[4]),  so2 = pkrtz_u(fkU[6], fkU[8]),
                 ee  = pkrtz_u(fkU[1], fkU[11]), eo  = pkrtz_u(fkU[0], fkU[10]);
        // k2 = 0: m = 2mc, rows 2mc..2mc+5 = pairs P0,P1,P2 (aligned)
        {
            unsigned w0[4];
#pragma unroll
            for (int j = 0; j < 4; ++j) {
                float ve = __builtin_amdgcn_fdot2(u2g(a0[j]), u2g(te0), 0.f, false);
                ve = __builtin_amdgcn_fdot2(u2g(a1[j]), u2g(te1), ve, false);
                ve = __builtin_amdgcn_fdot2(u2g(a2[j]), u2g(te2), ve, false);
                float vo = __builtin_amdgcn_fdot2(u2g(a0[j]), u2g(to0), 0.f, false);
                vo = __builtin_amdgcn_fdot2(u2g(a1[j]), u2g(to1), vo, false);
                vo = __builtin_amdgcn_fdot2(u2g(a2[j]), u2g(to2), vo, false);
                w0[j] = pkrtz_u(ve, vo);
            }
            *(uint4*)(smemu + VS2 + (2 * mc) * VSS2 + 4 * cq)
                = make_uint4(w0[0], w0[1], w0[2], w0[3]);
        }
        // k2 = 1: m = 2mc+1, rows 2mc+1..2mc+6 = hi(P0), P1, P2, lo(P3)
        if (2 * mc + 1 < 37) {
            unsigned w1[4];
#pragma unroll
            for (int j = 0; j < 4; ++j) {
                unsigned edge = pack2(u2h(a0[j]).y, u2h(a3[j]).x);
                float ve = __builtin_amdgcn_fdot2(u2g(a1[j]), u2g(se1), 0.f, false);
                ve = __builtin_amdgcn_fdot2(u2g(a2[j]), u2g(se2), ve, false);
                ve = __builtin_amdgcn_fdot2(u2g(edge),  u2g(ee),  ve, false);
                float vo = __builtin_amdgcn_fdot2(u2g(a1[j]), u2g(so1), 0.f, false);
                vo = __builtin_amdgcn_fdot2(u2g(a2[j]), u2g(so2), vo, false);
                vo = __builtin_amdgcn_fdot2(u2g(edge),  u2g(eo),  vo, false);
                w1[j] = pkrtz_u(ve, vo);
            }
            *(uint4*)(smemu + VS2 + (2 * mc + 1) * VSS2 + 4 * cq)
                = make_uint4(w1[0], w1[1], w1[2], w1[3]);
        }
    }
    __syncthreads();

    // ---- B: horizontal up + lrelu (VS2 f16 -> ZS f16), packed f16 FMA ----
    // task=(m<37, chunk q<5): z rows 2m,2m+1, cols 16q..16q+15.
    if (tid < 185) {
        int q = tid % 5, m = tid / 5;
        const unsigned* vb = smemu + VS2 + m * VSS2 + 8 * q;
        uint4 rr0 = *(const uint4*)(vb);
        uint4 rr1 = *(const uint4*)(vb + 4);
        uint4 rr2 = *(const uint4*)(vb + 8);
        uint2 rr3 = *(const uint2*)(vb + 12);
        h2 vc[14] = { u2h(rr0.x), u2h(rr0.y), u2h(rr0.z), u2h(rr0.w),
                      u2h(rr1.x), u2h(rr1.y), u2h(rr1.z), u2h(rr1.w),
                      u2h(rr2.x), u2h(rr2.y), u2h(rr2.z), u2h(rr2.w),
                      u2h(rr3.x), u2h(rr3.y) };
        h2 fo[6], fe[6];
#pragma unroll
        for (int s = 0; s < 6; ++s) { fo[s] = h2s(fkU[2*s+1]); fe[s] = h2s(fkU[2*s]); }
        h2 sl = h2s(0.01f);
        unsigned pk0[8], pk1[8];
#pragma unroll
        for (int h = 0; h < 8; ++h) {        // z cols 16q+2h (even), +1 (odd)
            h2 ae = h2s(0.f), ao = h2s(0.f); // lanes: .x=row 2m, .y=row 2m+1
#pragma unroll
            for (int s = 0; s < 6; ++s) {
                ae += vc[h + s] * fo[s];
                ao += vc[h + s] * fe[s];
            }
            ae = __builtin_elementwise_max(ae, ae * sl);
            ao = __builtin_elementwise_max(ao, ao * sl);
            pk0[h] = pack2(ae.x, ao.x);      // row 2m:   (z_even, z_odd)
            pk1[h] = pack2(ae.y, ao.y);      // row 2m+1: (z_even, z_odd)
        }
        unsigned* z0 = smemu + ZS + (2 * m) * ZSS + 8 * q;
        unsigned* z1 = z0 + ZSS;
        *(uint4*)(z0)     = make_uint4(pk0[0], pk0[1], pk0[2], pk0[3]);
        *(uint4*)(z0 + 4) = make_uint4(pk0[4], pk0[5], pk0[6], pk0[7]);
        *(uint4*)(z1)     = make_uint4(pk1[0], pk1[1], pk1[2], pk1[3]);
        *(uint4*)(z1 + 4) = make_uint4(pk1[4], pk1[5], pk1[6], pk1[7]);
    }
    __syncthreads();

    // ---- C: vertical down (ZS f16 -> WS f16), 4 out rows/task ----
    // task=(col-oct p8<10, row-quad hq<8); reads z rows 8hq..8hq+17.
    if (tid < 80) {
        int p8 = tid % 10, hq = tid / 10;
        h2 fkh[TAPS];
#pragma unroll
        for (int t = 0; t < TAPS; ++t) fkh[t] = h2s(0.5f * fkU[t]);
        h2 acc[4][4];
#pragma unroll
        for (int j = 0; j < 4; ++j)
#pragma unroll
            for (int d = 0; d < 4; ++d) acc[j][d] = h2s(0.f);
        const unsigned* zbase = smemu + ZS + (8 * hq) * ZSS + 4 * p8;
#pragma unroll
        for (int u = 0; u < 18; ++u) {
            uint4 zr = *(const uint4*)(zbase + u * ZSS);
            h2 z0 = u2h(zr.x), z1 = u2h(zr.y), z2 = u2h(zr.z), z3 = u2h(zr.w);
#pragma unroll
            for (int j = 0; j < 4; ++j) {
                int t = u - 2 * j;
                if (t >= 0 && t < TAPS) {
                    h2 tt = fkh[t];
                    acc[j][0] += tt * z0; acc[j][1] += tt * z1;
                    acc[j][2] += tt * z2; acc[j][3] += tt * z3;
                }
            }
        }
        unsigned* wp = smemu + WS + (4 * hq) * WSS + 4 * p8;
#pragma unroll
        for (int j = 0; j < 4; ++j)
            *(uint4*)(wp + j * WSS) = make_uint4(h2du(acc[j][0]), h2du(acc[j][1]),
                                                 h2du(acc[j][2]), h2du(acc[j][3]));
    }
    __syncthreads();

    // ---- D: horizontal down (WS f16 -> global f32) via v_dot2_f32_f16 ----
    {
        int ho = tid >> 3, w4 = tid & 7;
        const unsigned* wp = smemu + WS + ho * WSS + 4 * w4;
        uint4 q0 = *(const uint4*)(wp);
        uint4 q1 = *(const uint4*)(wp + 4);
        unsigned q2 = wp[8];
        unsigned dws[9] = { q0.x, q0.y, q0.z, q0.w, q1.x, q1.y, q1.z, q1.w, q2 };
        unsigned fp[6];
#pragma unroll
        for (int d = 0; d < 6; ++d) fp[d] = pkrtz_u(0.5f * fkU[2*d], 0.5f * fkU[2*d+1]);
        float o[4];
#pragma unroll
        for (int v = 0; v < 4; ++v) {
            float acc = 0.f;
#pragma unroll
            for (int d = 0; d < 6; ++d)
                acc = __builtin_amdgcn_fdot2(u2g(dws[v + d]), u2g(fp[d]), acc, false);
            o[v] = acc;
        }
        *(float4*)(out + ((size_t)nc * 128 + (ho0 + ho)) * 128 + wo0 + 4 * w4)
            = make_float4(o[0], o[1], o[2], o[3]);
    }
}

extern "C" void kernel_launch(void* const* d_in, const int* in_sizes, int n_in,
                              void* d_out, int out_size, void* d_ws, size_t ws_size,
                              hipStream_t stream) {
    const float* x = (const float*)d_in[0];
    const float* f = (const float*)d_in[1];
    float* out = (float*)d_out;
    dim3 grid(16, 1024);
    flrelu_fused<<<grid, 256, 0, stream>>>(x, f, out);
}